// Round 6
// baseline (1202.275 us; speedup 1.0000x reference)
//
#include <hip/hip_runtime.h>

#define DIM 1024
#define NKN 65536
#define TOK 4096
#define CK 20
#define FK 10
#define RNK 128
#define CAP 256
#define NCHUNK 256   // 65536 / 256 cols per GEMM block

typedef __bf16 v8bf __attribute__((ext_vector_type(8)));
typedef float v4f __attribute__((ext_vector_type(4)));

#define AS1 __attribute__((address_space(1)))
#define AS3 __attribute__((address_space(3)))

__device__ __forceinline__ unsigned short f2bf(float f) {
  // round-to-nearest-even fp32 -> bf16 (finite inputs only)
  unsigned u = __builtin_bit_cast(unsigned, f);
  u += 0x7FFFu + ((u >> 16) & 1u);
  return (unsigned short)(u >> 16);
}
__device__ __forceinline__ unsigned short bf2key(unsigned short b) {
  // monotone order-preserving key for bf16 bits
  return (b & 0x8000) ? (unsigned short)(~b) : (unsigned short)(b | 0x8000);
}

// ---------------------------------------------------------------------------
// K1: transpose W_router [DIM][NKN] -> WT fp32 [NKN][DIM] and WT bf16 [NKN][DIM]
// ---------------------------------------------------------------------------
__global__ __launch_bounds__(256) void k_transpose(const float* __restrict__ W,
                                                   float* __restrict__ WT,
                                                   unsigned short* __restrict__ WTb) {
  __shared__ float tile[32][33];
  const int n0 = (blockIdx.x & 2047) << 5;
  const int d0 = (blockIdx.x >> 11) << 5;
  const int c = threadIdx.x & 31, r0 = threadIdx.x >> 5;
#pragma unroll
  for (int i = 0; i < 4; i++) {
    int r = r0 + i * 8;
    tile[r][c] = W[(size_t)(d0 + r) * NKN + n0 + c];
  }
  __syncthreads();
#pragma unroll
  for (int i = 0; i < 4; i++) {
    int r = r0 + i * 8;
    float v = tile[c][r];  // = W[d0+c][n0+r]
    size_t o = (size_t)(n0 + r) * DIM + d0 + c;
    WT[o] = v;
    WTb[o] = f2bf(v);
  }
}

// ---------------------------------------------------------------------------
// K1b: convert x fp32 -> bf16
// ---------------------------------------------------------------------------
__global__ __launch_bounds__(256) void k_cvt_x(const float* __restrict__ x,
                                               unsigned short* __restrict__ xb) {
  const int i = blockIdx.x * 256 + threadIdx.x;
  const float4 v = reinterpret_cast<const float4*>(x)[i];
  ushort4 o;
  o.x = f2bf(v.x); o.y = f2bf(v.y); o.z = f2bf(v.z); o.w = f2bf(v.w);
  reinterpret_cast<ushort4*>(xb)[i] = o;
}

// ---------------------------------------------------------------------------
// K2: deep-pipelined bf16 MFMA GEMM (T3+T4+T5), 2 phases per K-tile,
// 16-MFMA clusters (m201 cluster size), B-frags held in regs across phases.
// 256x256 tile, BK=32, 512 threads = 8 waves (2M x 4N), per-wave C = 128x64.
// LDS = 4-slot ring (4 x 32 KiB), prefetch distance 3 K-tiles.
// Per tile: {vmcnt(8); barrier; [dsB0-3+dsA0-3 | stage A-rounds | barrier |
// lgkmcnt(0)+schedbar | prio1 16 MFMA prio0 | barrier] [dsA4-7 | stage
// B-rounds | barrier | lgkmcnt(0)+schedbar | prio1 16 MFMA prio0]} -- 4
// barriers/32K (m201 density), vmcnt never 0 in steady state.
// Ring safety: tile t reads slot t&3; stages during tile t write slot
// (t+3)&3 (distinct mod 4); per-wave vmcnt + top barrier publish cross-wave.
// LDS layout: 64-B rows, 4 x 16-B slots, phys slot = logical ^ perm; per
// 16-lane group each bank hit exactly 2x (free). Rule-21: linear gload_lds
// dest + inverse-permuted global src + same permutation on ds_read.
// ---------------------------------------------------------------------------
__global__ __launch_bounds__(512, 2) void k_gemm(const unsigned short* __restrict__ A,
                                                 const unsigned short* __restrict__ Bt,
                                                 unsigned short* __restrict__ Lg,
                                                 unsigned short* __restrict__ CmaxT) {
  __shared__ __align__(16) char lds[131072];  // ring[4]: {A 16 KB, B 16 KB}
  const int tid = threadIdx.x;
  const int lane = tid & 63, wid = tid >> 6;
  const int wm = wid >> 2, wn = wid & 3;
  const int mb = blockIdx.x & 15, nb = blockIdx.x >> 4;  // m-fast: B-panel reuse
  const int m0 = mb << 8, n0 = nb << 8;
  const int rm = lane & 15, lq = lane >> 4;
  v4f acc[8][4] = {};

  // staging source (inverse-permuted): thread covers phys row tid>>2, slot tid&3
  const int u8 = (((tid & 3) ^ ((tid >> 3) & 3)) << 3);
  const unsigned short* aSrc = A + (size_t)(m0 + (tid >> 2)) * DIM + u8;
  const unsigned short* bSrc = Bt + (size_t)(n0 + (tid >> 2)) * DIM + u8;

  // ds_read byte offsets within a slot (sx = permuted 16-B slot select)
  const int sx = ((lq ^ ((rm >> 1) & 3)) << 4);
  const int aOff = (wm * 128 + rm) * 64 + sx;            // + fr*1024
  const int bOff = 16384 + (wn * 64 + rm) * 64 + sx;     // + nf*1024

  // prologue: stage tiles 0,1,2 (12 loads in flight)
#pragma unroll
  for (int tt = 0; tt < 3; ++tt) {
    char* base = lds + tt * 32768 + wid * 1024;
    const unsigned short* as = aSrc + tt * 32;
    const unsigned short* bs = bSrc + tt * 32;
    __builtin_amdgcn_global_load_lds((const AS1 void*)as, (AS3 void*)base, 16, 0, 0);
    __builtin_amdgcn_global_load_lds((const AS1 void*)(as + 128 * DIM), (AS3 void*)(base + 8192), 16, 0, 0);
    __builtin_amdgcn_global_load_lds((const AS1 void*)bs, (AS3 void*)(base + 16384), 16, 0, 0);
    __builtin_amdgcn_global_load_lds((const AS1 void*)(bs + 128 * DIM), (AS3 void*)(base + 24576), 16, 0, 0);
  }

#define MM(FR, AREG) \
  acc[FR][0] = __builtin_amdgcn_mfma_f32_16x16x32_bf16(AREG, b0, acc[FR][0], 0, 0, 0); \
  acc[FR][1] = __builtin_amdgcn_mfma_f32_16x16x32_bf16(AREG, b1, acc[FR][1], 0, 0, 0); \
  acc[FR][2] = __builtin_amdgcn_mfma_f32_16x16x32_bf16(AREG, b2, acc[FR][2], 0, 0, 0); \
  acc[FR][3] = __builtin_amdgcn_mfma_f32_16x16x32_bf16(AREG, b3, acc[FR][3], 0, 0, 0);

#define TILE(T, VM, DOSTAGE) do { \
    asm volatile("s_waitcnt vmcnt(" VM ")" ::: "memory"); \
    __builtin_amdgcn_s_barrier(); \
    const char* sb = lds + ((T) & 3) * 32768; \
    char* stb = lds + (((T) + 3) & 3) * 32768 + wid * 1024; \
    const unsigned short* sa = aSrc + ((T) + 3) * 32; \
    const unsigned short* sg = bSrc + ((T) + 3) * 32; \
    /* phase A: read all 4 B-frags (held) + A-frags 0-3; stage A rounds */ \
    v8bf b0 = *(const v8bf*)(sb + bOff); \
    v8bf b1 = *(const v8bf*)(sb + bOff + 1024); \
    v8bf b2 = *(const v8bf*)(sb + bOff + 2048); \
    v8bf b3 = *(const v8bf*)(sb + bOff + 3072); \
    v8bf a0 = *(const v8bf*)(sb + aOff); \
    v8bf a1 = *(const v8bf*)(sb + aOff + 1024); \
    v8bf a2 = *(const v8bf*)(sb + aOff + 2048); \
    v8bf a3 = *(const v8bf*)(sb + aOff + 3072); \
    if (DOSTAGE) { \
      __builtin_amdgcn_global_load_lds((const AS1 void*)sa, (AS3 void*)stb, 16, 0, 0); \
      __builtin_amdgcn_global_load_lds((const AS1 void*)(sa + 128 * DIM), (AS3 void*)(stb + 8192), 16, 0, 0); \
    } \
    __builtin_amdgcn_s_barrier(); \
    asm volatile("s_waitcnt lgkmcnt(0)" ::: "memory"); \
    __builtin_amdgcn_sched_barrier(0); \
    __builtin_amdgcn_s_setprio(1); \
    MM(0, a0) MM(1, a1) MM(2, a2) MM(3, a3) \
    __builtin_amdgcn_s_setprio(0); \
    __builtin_amdgcn_s_barrier(); \
    /* phase B: read A-frags 4-7 (B still in regs); stage B rounds */ \
    a0 = *(const v8bf*)(sb + aOff + 4096); \
    a1 = *(const v8bf*)(sb + aOff + 5120); \
    a2 = *(const v8bf*)(sb + aOff + 6144); \
    a3 = *(const v8bf*)(sb + aOff + 7168); \
    if (DOSTAGE) { \
      __builtin_amdgcn_global_load_lds((const AS1 void*)sg, (AS3 void*)(stb + 16384), 16, 0, 0); \
      __builtin_amdgcn_global_load_lds((const AS1 void*)(sg + 128 * DIM), (AS3 void*)(stb + 24576), 16, 0, 0); \
    } \
    __builtin_amdgcn_s_barrier(); \
    asm volatile("s_waitcnt lgkmcnt(0)" ::: "memory"); \
    __builtin_amdgcn_sched_barrier(0); \
    __builtin_amdgcn_s_setprio(1); \
    MM(4, a0) MM(5, a1) MM(6, a2) MM(7, a3) \
    __builtin_amdgcn_s_setprio(0); \
  } while (0)

  for (int t = 0; t < 30; ++t) {
    TILE(t, "8", (t < 29));
  }
  TILE(30, "4", false);
  TILE(31, "0", false);
#undef TILE
#undef MM

  // ---- epilogue ----
  // C/D layout (verified m89/m91): n = rm, m = lq*4 + reg
  const int mr = lq * 4;
  float rmax[8][4];
#pragma unroll
  for (int fr = 0; fr < 8; ++fr) {
#pragma unroll
    for (int r = 0; r < 4; ++r) {
      float mx = acc[fr][0][r];
#pragma unroll
      for (int nf = 1; nf < 4; ++nf) mx = fmaxf(mx, acc[fr][nf][r]);
      rmax[fr][r] = mx;
    }
#pragma unroll
    for (int nf = 0; nf < 4; ++nf) {
      const int mrow = m0 + wm * 128 + fr * 16 + mr;
      const int ncol = n0 + wn * 64 + nf * 16 + rm;
#pragma unroll
      for (int r = 0; r < 4; ++r)
        Lg[(size_t)(mrow + r) * NKN + ncol] = f2bf(acc[fr][nf][r]);
    }
  }
  // reduce row-max across the 16 rm lanes (xor<16 stays within the group)
#pragma unroll
  for (int fr = 0; fr < 8; ++fr)
#pragma unroll
    for (int r = 0; r < 4; ++r) {
#pragma unroll
      for (int off = 1; off < 16; off <<= 1)
        rmax[fr][r] = fmaxf(rmax[fr][r], __shfl_xor(rmax[fr][r], off));
    }
  // cross-wave (wn) reduce via LDS slot 0 (last read at tile 28; safe)
  float* smax = (float*)lds;  // [4][256]
  if (rm == 0) {
#pragma unroll
    for (int fr = 0; fr < 8; ++fr)
#pragma unroll
      for (int r = 0; r < 4; ++r)
        smax[wn * 256 + wm * 128 + fr * 16 + mr + r] = rmax[fr][r];
  }
  __syncthreads();
  if (tid < 256) {
    float v = fmaxf(fmaxf(smax[tid], smax[256 + tid]),
                    fmaxf(smax[512 + tid], smax[768 + tid]));
    CmaxT[(size_t)nb * TOK + m0 + tid] = bf2key(f2bf(v));
  }
}

// ---------------------------------------------------------------------------
// K3: per-token candidate pick from chunk maxes (CmaxT layout [NCHUNK][TOK]).
// tau = 32nd-largest chunk-max key; collect all entries with key>>4 >= tau>>4
// (superset of true top-32: every top-32 element >= tau). Reads only
// qualifying 256-col chunks.
// ---------------------------------------------------------------------------
__global__ __launch_bounds__(256) void k_pick(const unsigned short* __restrict__ CmaxT,
                                              const unsigned short* __restrict__ Lg,
                                              int* __restrict__ cidx,
                                              int* __restrict__ ccnt) {
  __shared__ unsigned short keys[NCHUNK];
  __shared__ int qlist[NCHUNK];
  __shared__ int qn, scnt, bsS;
  const int t = blockIdx.x, tid = threadIdx.x;
  const int lane = tid & 63, w = tid >> 6;
  keys[tid] = CmaxT[(size_t)tid * TOK + t];
  if (tid == 0) { qn = 0; scnt = 0; }
  __syncthreads();
  if (w == 0) {
    int v[4];
#pragma unroll
    for (int j = 0; j < 4; j++) v[j] = keys[lane * 4 + j];
    int t32 = 0;
    for (int it = 0; it < 32; it++) {
      int lm = v[0];
#pragma unroll
      for (int j = 1; j < 4; j++) lm = max(lm, v[j]);
      int gm = lm;
#pragma unroll
      for (int off = 32; off > 0; off >>= 1) gm = max(gm, __shfl_xor(gm, off));
      unsigned long long msk = __ballot(lm == gm);
      if (lane == __ffsll((long long)msk) - 1) {
        bool done = false;
#pragma unroll
        for (int j = 0; j < 4; j++)
          if (!done && v[j] == gm) { v[j] = -1; done = true; }
      }
      t32 = gm;
    }
    if (lane == 0) bsS = t32 >> 4;
  }
  __syncthreads();
  const int bs = bsS;
  if ((keys[tid] >> 4) >= bs) { int p = atomicAdd(&qn, 1); qlist[p] = tid; }
  __syncthreads();
  const int nq = qn;
  for (int qi = 0; qi < nq; qi++) {
    const int col = qlist[qi] * 256 + tid;
    unsigned short key = bf2key(Lg[(size_t)t * NKN + col]);
    if ((int)(key >> 4) >= bs) {
      int p = atomicAdd(&scnt, 1);
      if (p < CAP) cidx[(size_t)t * CAP + p] = col;
    }
  }
  __syncthreads();
  if (tid == 0) ccnt[t] = min(scnt, CAP);
}

// ---------------------------------------------------------------------------
// K4: exact fp64 rescore of candidates + exact top-20 selection
// ---------------------------------------------------------------------------
__global__ __launch_bounds__(256) void k_rescore(const float* __restrict__ x,
                                                 const float* __restrict__ WT,
                                                 const int* __restrict__ cidx,
                                                 const int* __restrict__ ccnt,
                                                 int* __restrict__ coarse) {
  __shared__ float xs[DIM];
  __shared__ double sc[CAP];
  __shared__ int ci[CAP];
  const int t = blockIdx.x, tid = threadIdx.x;
  const int lane = tid & 63, w = tid >> 6;
  const int cnt = ccnt[t];
  for (int i = tid; i < DIM; i += 256) xs[i] = x[(size_t)t * DIM + i];
  for (int i = tid; i < CAP; i += 256) {
    sc[i] = -1e300;
    ci[i] = (i < cnt) ? cidx[(size_t)t * CAP + i] : 0;
  }
  __syncthreads();
  for (int c = w; c < cnt; c += 4) {
    const float* wr = WT + (size_t)ci[c] * DIM;
    double sacc = 0.0;
#pragma unroll 4
    for (int i = lane; i < DIM; i += 64) sacc += (double)xs[i] * (double)wr[i];
#pragma unroll
    for (int off = 32; off > 0; off >>= 1) sacc += __shfl_down(sacc, off);
    if (lane == 0) sc[c] = sacc;
  }
  __syncthreads();
  if (w == 0) {
    double v[4];
    int ix[4];
#pragma unroll
    for (int j = 0; j < 4; j++) { v[j] = sc[lane + j * 64]; ix[j] = lane + j * 64; }
    for (int kk = 0; kk < CK; kk++) {
      double v1 = v[0]; int i1 = ix[0];
#pragma unroll
      for (int j = 1; j < 4; j++)
        if (v[j] > v1) { v1 = v[j]; i1 = ix[j]; }
#pragma unroll
      for (int off = 32; off > 0; off >>= 1) {
        double ov = __shfl_down(v1, off);
        int oi = __shfl_down(i1, off);
        if (ov > v1) { v1 = ov; i1 = oi; }
      }
      i1 = __shfl(i1, 0);
      if (lane == 0) coarse[(size_t)t * CK + kk] = ci[i1];
#pragma unroll
      for (int j = 0; j < 4; j++)
        if (i1 == ix[j]) v[j] = -1e300;
    }
  }
}

// ---------------------------------------------------------------------------
// K5: query = x @ W_enc
// ---------------------------------------------------------------------------
__global__ __launch_bounds__(128) void k_query(const float* __restrict__ x,
                                               const float* __restrict__ Wenc,
                                               float* __restrict__ q) {
  const int j = threadIdx.x;
  const int t0 = blockIdx.x * 4;
  float s0 = 0.f, s1 = 0.f, s2 = 0.f, s3 = 0.f;
  const float* x0 = x + (size_t)t0 * DIM;
  for (int d = 0; d < DIM; d++) {
    float wv = Wenc[d * RNK + j];
    s0 = fmaf(x0[d], wv, s0);
    s1 = fmaf(x0[DIM + d], wv, s1);
    s2 = fmaf(x0[2 * DIM + d], wv, s2);
    s3 = fmaf(x0[3 * DIM + d], wv, s3);
  }
  q[(size_t)t0 * RNK + j] = s0;
  q[(size_t)(t0 + 1) * RNK + j] = s1;
  q[(size_t)(t0 + 2) * RNK + j] = s2;
  q[(size_t)(t0 + 3) * RNK + j] = s3;
}

// ---------------------------------------------------------------------------
// K6: fine scores vs 20 candidates, top-10, softmax, weighted V blend
// ---------------------------------------------------------------------------
__global__ __launch_bounds__(256) void k_fine(const float* __restrict__ q,
                                              const float* __restrict__ Kall,
                                              const float* __restrict__ Vall,
                                              const int* __restrict__ coarse,
                                              float* __restrict__ out) {
  __shared__ float qs[RNK];
  __shared__ float fsc[CK];
  __shared__ int gix[CK];
  __shared__ float wts[FK];
  __shared__ int fidx[FK];
  const int t = blockIdx.x, tid = threadIdx.x;
  const int lane = tid & 63, w = tid >> 6;
  if (tid < RNK) qs[tid] = q[(size_t)t * RNK + tid];
  if (tid < CK) gix[tid] = coarse[(size_t)t * CK + tid];
  __syncthreads();
  for (int c = w; c < CK; c += 4) {
    const float* kr = Kall + (size_t)gix[c] * RNK;
    float s = 0.f;
    s = fmaf(qs[lane], kr[lane], s);
    s = fmaf(qs[lane + 64], kr[lane + 64], s);
#pragma unroll
    for (int off = 32; off > 0; off >>= 1) s += __shfl_down(s, off);
    if (lane == 0) fsc[c] = s * 0.08838834764831843f;  // 1/sqrt(128)
  }
  __syncthreads();
  if (w == 0) {
    float vv = (lane < CK) ? fsc[lane] : -3e38f;
    float myv = -3e38f; int myp = 0;
    for (int kk = 0; kk < FK; kk++) {
      float v1 = vv; int p1 = lane;
#pragma unroll
      for (int off = 32; off > 0; off >>= 1) {
        float ov = __shfl_down(v1, off);
        int op = __shfl_down(p1, off);
        if (ov > v1) { v1 = ov; p1 = op; }
      }
      v1 = __shfl(v1, 0); p1 = __shfl(p1, 0);
      if (lane == kk) { myv = v1; myp = p1; }
      if (lane == p1) vv = -3e38f;
    }
    float sv = (lane < FK) ? myv : -3e38f;
    float mx = sv;
#pragma unroll
    for (int off = 8; off > 0; off >>= 1) mx = fmaxf(mx, __shfl_xor(mx, off, 16));
    float e = (lane < FK) ? expf(sv - mx) : 0.f;
    float se = e;
#pragma unroll
    for (int off = 8; off > 0; off >>= 1) se += __shfl_xor(se, off, 16);
    if (lane < FK) { wts[lane] = e / se; fidx[lane] = gix[myp]; }
  }
  __syncthreads();
  float4 a = make_float4(0.f, 0.f, 0.f, 0.f);
#pragma unroll
  for (int f = 0; f < FK; f++) {
    const float wt = wts[f];
    const float4 v = *reinterpret_cast<const float4*>(&Vall[(size_t)fidx[f] * DIM + tid * 4]);
    a.x = fmaf(wt, v.x, a.x);
    a.y = fmaf(wt, v.y, a.y);
    a.z = fmaf(wt, v.z, a.z);
    a.w = fmaf(wt, v.w, a.w);
  }
  *reinterpret_cast<float4*>(&out[(size_t)t * DIM + tid * 4]) = a;
}

// ---------------------------------------------------------------------------

extern "C" void kernel_launch(void* const* d_in, const int* in_sizes, int n_in,
                              void* d_out, int out_size, void* d_ws, size_t ws_size,
                              hipStream_t stream) {
  const float* x = (const float*)d_in[0];      // [4096][1024]
  const float* Wr = (const float*)d_in[1];     // [1024][65536]
  const float* Wenc = (const float*)d_in[2];   // [1024][128]
  const float* Kall = (const float*)d_in[3];   // [65536][128]
  const float* Vall = (const float*)d_in[4];   // [65536][1024]
  float* out = (float*)d_out;                  // [4096][1024]

  char* ws = (char*)d_ws;
  constexpr size_t OFF_WT = 0;                  // fp32 W^T    256 MB (live until rescore)
  constexpr size_t OFF_WTB = 268435456;         // bf16 W^T    128 MB (dead after gemm)
  constexpr size_t OFF_XB = 402653184;          // bf16 x        8 MB (dead after gemm)
  constexpr size_t OFF_LG = 411041792;          // bf16 logits 512 MB
  constexpr size_t OFF_CMAX = 947912704;        // chunk-max keys 2 MB (4 MB reserved)
  float* WT = (float*)(ws + OFF_WT);
  unsigned short* WTb = (unsigned short*)(ws + OFF_WTB);
  unsigned short* xb = (unsigned short*)(ws + OFF_XB);
  unsigned short* Lg = (unsigned short*)(ws + OFF_LG);
  unsigned short* CmaxT = (unsigned short*)(ws + OFF_CMAX);
  // aliases into regions that are dead after k_gemm:
  int* cidx = (int*)(ws + OFF_XB);                        // 4 MB
  int* ccnt = (int*)(ws + OFF_XB + 4194304);              // 16 KB
  int* coarse = (int*)(ws + OFF_XB + 4259840);            // 320 KB
  float* q = (float*)(ws + OFF_WTB);                      // 2 MB

  k_transpose<<<65536, 256, 0, stream>>>(Wr, WT, WTb);
  k_cvt_x<<<4096, 256, 0, stream>>>(x, xb);
  k_gemm<<<4096, 512, 0, stream>>>(xb, WTb, Lg, CmaxT);
  k_pick<<<4096, 256, 0, stream>>>(CmaxT, Lg, cidx, ccnt);
  k_rescore<<<4096, 256, 0, stream>>>(x, WT, cidx, ccnt, coarse);
  k_query<<<1024, 128, 0, stream>>>(x, Wenc, q);
  k_fine<<<4096, 256, 0, stream>>>(q, Kall, Vall, coarse, out);
}

// Round 7
// 1058.597 us; speedup vs baseline: 1.1357x; 1.1357x over previous
//
#include <hip/hip_runtime.h>

#define DIM 1024
#define NKN 65536
#define TOK 4096
#define CK 20
#define FK 10
#define RNK 128
#define CAP 256
#define NCHUNK 512   // 65536 / 128 cols per GEMM block

typedef __bf16 v8bf __attribute__((ext_vector_type(8)));
typedef float v4f __attribute__((ext_vector_type(4)));

#define AS1 __attribute__((address_space(1)))
#define AS3 __attribute__((address_space(3)))

__device__ __forceinline__ unsigned short f2bf(float f) {
  // round-to-nearest-even fp32 -> bf16 (finite inputs only)
  unsigned u = __builtin_bit_cast(unsigned, f);
  u += 0x7FFFu + ((u >> 16) & 1u);
  return (unsigned short)(u >> 16);
}
__device__ __forceinline__ unsigned short bf2key(unsigned short b) {
  // monotone order-preserving key for bf16 bits
  return (b & 0x8000) ? (unsigned short)(~b) : (unsigned short)(b | 0x8000);
}

// ---------------------------------------------------------------------------
// K1: transpose W_router [DIM][NKN] -> WT fp32 [NKN][DIM] and WT bf16 [NKN][DIM]
// ---------------------------------------------------------------------------
__global__ __launch_bounds__(256) void k_transpose(const float* __restrict__ W,
                                                   float* __restrict__ WT,
                                                   unsigned short* __restrict__ WTb) {
  __shared__ float tile[32][33];
  const int n0 = (blockIdx.x & 2047) << 5;
  const int d0 = (blockIdx.x >> 11) << 5;
  const int c = threadIdx.x & 31, r0 = threadIdx.x >> 5;
#pragma unroll
  for (int i = 0; i < 4; i++) {
    int r = r0 + i * 8;
    tile[r][c] = W[(size_t)(d0 + r) * NKN + n0 + c];
  }
  __syncthreads();
#pragma unroll
  for (int i = 0; i < 4; i++) {
    int r = r0 + i * 8;
    float v = tile[c][r];  // = W[d0+c][n0+r]
    size_t o = (size_t)(n0 + r) * DIM + d0 + c;
    WT[o] = v;
    WTb[o] = f2bf(v);
  }
}

// ---------------------------------------------------------------------------
// K1b: convert x fp32 -> bf16
// ---------------------------------------------------------------------------
__global__ __launch_bounds__(256) void k_cvt_x(const float* __restrict__ x,
                                               unsigned short* __restrict__ xb) {
  const int i = blockIdx.x * 256 + threadIdx.x;
  const float4 v = reinterpret_cast<const float4*>(x)[i];
  ushort4 o;
  o.x = f2bf(v.x); o.y = f2bf(v.y); o.z = f2bf(v.z); o.w = f2bf(v.w);
  reinterpret_cast<ushort4*>(xb)[i] = o;
}

// ---------------------------------------------------------------------------
// K2: bf16 MFMA GEMM, 2-blocks/CU geometry (break the 1-block lockstep).
// 256x128 tile, BK=32, 512 threads = 8 waves (4M x 2N), per-wave C = 64x64
// -> acc 4x4 frags = 64 AGPR; __launch_bounds__(512,4) targets <=128 total
// regs = 4 waves/SIMD = 2 independent blocks/CU (cross-block overlap hides
// barrier stalls, m114). LDS: 3-slot ring x 24 KB = 72 KB (2 blocks = 144).
// Prefetch distance 2, counted vmcnt(6)/(3)/(0), 2 barriers/tile.
// LDS layout: 64-B rows, phys 16B-slot = lq ^ (row&3) -> uniform 8 lanes per
// bank-quad (0 conflicts). Rule-21: linear gload_lds dest + inverse-permuted
// global src + same permutation on ds_read.
// Fused epilogue: per-row max over the block's 128 cols -> CmaxT[nb][row].
// ---------------------------------------------------------------------------
__global__ __launch_bounds__(512, 4) void k_gemm(const unsigned short* __restrict__ A,
                                                 const unsigned short* __restrict__ Bt,
                                                 unsigned short* __restrict__ Lg,
                                                 unsigned short* __restrict__ CmaxT) {
  __shared__ __align__(16) char lds[73728];  // ring[3]: {A 16 KB, B 8 KB}
  const int tid = threadIdx.x;
  const int lane = tid & 63, wid = tid >> 6;
  const int wm = wid >> 1, wn = wid & 1;
  const int mb = blockIdx.x & 15, nb = blockIdx.x >> 4;  // m-fast: B-panel reuse
  const int m0 = mb << 8, n0 = nb << 7;
  const int rm = lane & 15, lq = lane >> 4;
  v4f acc[4][4] = {};

  // staging (inverse-permuted src): phys row R = p*128 + (tid>>2), slot tid&3
  // logical k-slot u = (tid&3) ^ (R&3) = (tid&3) ^ ((tid>>2)&3)
  const int u8 = (((tid & 3) ^ ((tid >> 2) & 3)) << 3);
  const unsigned short* aSrc = A + (size_t)(m0 + (tid >> 2)) * DIM + u8;   // rows tid>>2, +128
  const unsigned short* bSrc = Bt + (size_t)(n0 + (tid >> 2)) * DIM + u8;  // rows tid>>2 (0..127)

  // ds_read byte offsets: row*64 + (lq ^ (row&3))*16 ; row&3 == rm&3
  const int sx = ((lq ^ (rm & 3)) << 4);
  const int aOff = (wm * 64 + rm) * 64 + sx;           // + fr*1024
  const int bOff = 16384 + (wn * 64 + rm) * 64 + sx;   // + nf*1024

#define STAGE(SLOT, KT) do { \
    char* _b = lds + (SLOT) * 24576 + tid * 16; \
    __builtin_amdgcn_global_load_lds((const AS1 void*)(aSrc + (KT)),             (AS3 void*)(_b),         16, 0, 0); \
    __builtin_amdgcn_global_load_lds((const AS1 void*)(aSrc + (KT) + 128 * DIM), (AS3 void*)(_b + 8192),  16, 0, 0); \
    __builtin_amdgcn_global_load_lds((const AS1 void*)(bSrc + (KT)),             (AS3 void*)(_b + 16384), 16, 0, 0); \
  } while (0)

#define TILE(T, VM, DOSTAGE) do { \
    if (DOSTAGE) STAGE(((T) + 2) % 3, ((T) + 2) * 32); \
    asm volatile("s_waitcnt vmcnt(" VM ")" ::: "memory"); \
    __builtin_amdgcn_s_barrier(); \
    const char* sb = lds + ((T) % 3) * 24576; \
    v8bf a0 = *(const v8bf*)(sb + aOff); \
    v8bf a1 = *(const v8bf*)(sb + aOff + 1024); \
    v8bf a2 = *(const v8bf*)(sb + aOff + 2048); \
    v8bf a3 = *(const v8bf*)(sb + aOff + 3072); \
    v8bf b0 = *(const v8bf*)(sb + bOff); \
    v8bf b1 = *(const v8bf*)(sb + bOff + 1024); \
    v8bf b2 = *(const v8bf*)(sb + bOff + 2048); \
    v8bf b3 = *(const v8bf*)(sb + bOff + 3072); \
    __builtin_amdgcn_s_setprio(1); \
    _Pragma("unroll") for (int nf = 0; nf < 4; ++nf) { \
      v8bf bb = (nf == 0) ? b0 : (nf == 1) ? b1 : (nf == 2) ? b2 : b3; \
      acc[0][nf] = __builtin_amdgcn_mfma_f32_16x16x32_bf16(a0, bb, acc[0][nf], 0, 0, 0); \
      acc[1][nf] = __builtin_amdgcn_mfma_f32_16x16x32_bf16(a1, bb, acc[1][nf], 0, 0, 0); \
      acc[2][nf] = __builtin_amdgcn_mfma_f32_16x16x32_bf16(a2, bb, acc[2][nf], 0, 0, 0); \
      acc[3][nf] = __builtin_amdgcn_mfma_f32_16x16x32_bf16(a3, bb, acc[3][nf], 0, 0, 0); \
    } \
    __builtin_amdgcn_s_setprio(0); \
    __builtin_amdgcn_s_barrier(); \
  } while (0)

  // prologue: stage tiles 0,1 (6 loads in flight)
  STAGE(0, 0);
  STAGE(1, 32);

  for (int t = 0; t < 30; ++t) {
    TILE(t, "6", true);
  }
  TILE(30, "3", false);
  TILE(31, "0", false);
#undef TILE
#undef STAGE

  // ---- epilogue ----
  // C/D layout (verified m89/m91): n = rm, m = lq*4 + reg
  const int mr = lq * 4;
  float rmax[4][4];
#pragma unroll
  for (int fr = 0; fr < 4; ++fr) {
#pragma unroll
    for (int r = 0; r < 4; ++r) {
      float mx = acc[fr][0][r];
#pragma unroll
      for (int nf = 1; nf < 4; ++nf) mx = fmaxf(mx, acc[fr][nf][r]);
      rmax[fr][r] = mx;
    }
#pragma unroll
    for (int nf = 0; nf < 4; ++nf) {
      const int mrow = m0 + wm * 64 + fr * 16 + mr;
      const int ncol = n0 + wn * 64 + nf * 16 + rm;
#pragma unroll
      for (int r = 0; r < 4; ++r)
        Lg[(size_t)(mrow + r) * NKN + ncol] = f2bf(acc[fr][nf][r]);
    }
  }
  // reduce row-max across the 16 rm lanes (xor<16 stays within the group)
#pragma unroll
  for (int fr = 0; fr < 4; ++fr)
#pragma unroll
    for (int r = 0; r < 4; ++r) {
#pragma unroll
      for (int off = 1; off < 16; off <<= 1)
        rmax[fr][r] = fmaxf(rmax[fr][r], __shfl_xor(rmax[fr][r], off));
    }
  // cross-wave (wn) combine via LDS (slot-0 region, all reads retired)
  __syncthreads();
  float* smax = (float*)lds;  // [2][256]
  if (rm == 0) {
#pragma unroll
    for (int fr = 0; fr < 4; ++fr)
#pragma unroll
      for (int r = 0; r < 4; ++r)
        smax[wn * 256 + wm * 64 + fr * 16 + mr + r] = rmax[fr][r];
  }
  __syncthreads();
  if (tid < 256) {
    float v = fmaxf(smax[tid], smax[256 + tid]);
    CmaxT[(size_t)nb * TOK + m0 + tid] = bf2key(f2bf(v));
  }
}

// ---------------------------------------------------------------------------
// K3: per-token candidate pick from chunk maxes (CmaxT layout [NCHUNK][TOK]).
// tau = 32nd-largest chunk-max key (EXACT, no bucket flooring); collect all
// entries with key >= tau. Superset of bf16-top-32 (every top-32 element >=
// tau since the 32 chunk-maxes are 32 distinct elements >= tau). Reads only
// qualifying 128-col chunks.
// ---------------------------------------------------------------------------
__global__ __launch_bounds__(256) void k_pick(const unsigned short* __restrict__ CmaxT,
                                              const unsigned short* __restrict__ Lg,
                                              int* __restrict__ cidx,
                                              int* __restrict__ ccnt) {
  __shared__ unsigned short keys[NCHUNK];
  __shared__ int qlist[NCHUNK];
  __shared__ int qn, scnt, bsS;
  const int t = blockIdx.x, tid = threadIdx.x;
  const int lane = tid & 63, w = tid >> 6;
  keys[tid] = CmaxT[(size_t)tid * TOK + t];
  keys[tid + 256] = CmaxT[(size_t)(tid + 256) * TOK + t];
  if (tid == 0) { qn = 0; scnt = 0; }
  __syncthreads();
  if (w == 0) {
    int v[8];
#pragma unroll
    for (int j = 0; j < 8; j++) v[j] = keys[lane * 8 + j];
    int t32 = 0;
    for (int it = 0; it < 32; it++) {
      int lm = v[0];
#pragma unroll
      for (int j = 1; j < 8; j++) lm = max(lm, v[j]);
      int gm = lm;
#pragma unroll
      for (int off = 32; off > 0; off >>= 1) gm = max(gm, __shfl_xor(gm, off));
      unsigned long long msk = __ballot(lm == gm);
      if (lane == __ffsll((long long)msk) - 1) {
        bool done = false;
#pragma unroll
        for (int j = 0; j < 8; j++)
          if (!done && v[j] == gm) { v[j] = -1; done = true; }
      }
      t32 = gm;
    }
    if (lane == 0) bsS = t32;
  }
  __syncthreads();
  const int bs = bsS;
  for (int c = tid; c < NCHUNK; c += 256)
    if ((int)keys[c] >= bs) { int p = atomicAdd(&qn, 1); qlist[p] = c; }
  __syncthreads();
  const int nq = qn;
  const int sub = tid >> 7, e = tid & 127;
  for (int qi = sub; qi < nq; qi += 2) {
    const int col = qlist[qi] * 128 + e;
    unsigned short key = bf2key(Lg[(size_t)t * NKN + col]);
    if ((int)key >= bs) {
      int p = atomicAdd(&scnt, 1);
      if (p < CAP) cidx[(size_t)t * CAP + p] = col;
    }
  }
  __syncthreads();
  if (tid == 0) ccnt[t] = min(scnt, CAP);
}

// ---------------------------------------------------------------------------
// K4: exact fp64 rescore of candidates + exact top-20 selection
// ---------------------------------------------------------------------------
__global__ __launch_bounds__(256) void k_rescore(const float* __restrict__ x,
                                                 const float* __restrict__ WT,
                                                 const int* __restrict__ cidx,
                                                 const int* __restrict__ ccnt,
                                                 int* __restrict__ coarse) {
  __shared__ float xs[DIM];
  __shared__ double sc[CAP];
  __shared__ int ci[CAP];
  const int t = blockIdx.x, tid = threadIdx.x;
  const int lane = tid & 63, w = tid >> 6;
  const int cnt = ccnt[t];
  for (int i = tid; i < DIM; i += 256) xs[i] = x[(size_t)t * DIM + i];
  for (int i = tid; i < CAP; i += 256) {
    sc[i] = -1e300;
    ci[i] = (i < cnt) ? cidx[(size_t)t * CAP + i] : 0;
  }
  __syncthreads();
  for (int c = w; c < cnt; c += 4) {
    const float* wr = WT + (size_t)ci[c] * DIM;
    double sacc = 0.0;
#pragma unroll 4
    for (int i = lane; i < DIM; i += 64) sacc += (double)xs[i] * (double)wr[i];
#pragma unroll
    for (int off = 32; off > 0; off >>= 1) sacc += __shfl_down(sacc, off);
    if (lane == 0) sc[c] = sacc;
  }
  __syncthreads();
  if (w == 0) {
    double v[4];
    int ix[4];
#pragma unroll
    for (int j = 0; j < 4; j++) { v[j] = sc[lane + j * 64]; ix[j] = lane + j * 64; }
    for (int kk = 0; kk < CK; kk++) {
      double v1 = v[0]; int i1 = ix[0];
#pragma unroll
      for (int j = 1; j < 4; j++)
        if (v[j] > v1) { v1 = v[j]; i1 = ix[j]; }
#pragma unroll
      for (int off = 32; off > 0; off >>= 1) {
        double ov = __shfl_down(v1, off);
        int oi = __shfl_down(i1, off);
        if (ov > v1) { v1 = ov; i1 = oi; }
      }
      i1 = __shfl(i1, 0);
      if (lane == 0) coarse[(size_t)t * CK + kk] = ci[i1];
#pragma unroll
      for (int j = 0; j < 4; j++)
        if (i1 == ix[j]) v[j] = -1e300;
    }
  }
}

// ---------------------------------------------------------------------------
// K5: query = x @ W_enc
// ---------------------------------------------------------------------------
__global__ __launch_bounds__(128) void k_query(const float* __restrict__ x,
                                               const float* __restrict__ Wenc,
                                               float* __restrict__ q) {
  const int j = threadIdx.x;
  const int t0 = blockIdx.x * 4;
  float s0 = 0.f, s1 = 0.f, s2 = 0.f, s3 = 0.f;
  const float* x0 = x + (size_t)t0 * DIM;
  for (int d = 0; d < DIM; d++) {
    float wv = Wenc[d * RNK + j];
    s0 = fmaf(x0[d], wv, s0);
    s1 = fmaf(x0[DIM + d], wv, s1);
    s2 = fmaf(x0[2 * DIM + d], wv, s2);
    s3 = fmaf(x0[3 * DIM + d], wv, s3);
  }
  q[(size_t)t0 * RNK + j] = s0;
  q[(size_t)(t0 + 1) * RNK + j] = s1;
  q[(size_t)(t0 + 2) * RNK + j] = s2;
  q[(size_t)(t0 + 3) * RNK + j] = s3;
}

// ---------------------------------------------------------------------------
// K6: fine scores vs 20 candidates, top-10, softmax, weighted V blend
// ---------------------------------------------------------------------------
__global__ __launch_bounds__(256) void k_fine(const float* __restrict__ q,
                                              const float* __restrict__ Kall,
                                              const float* __restrict__ Vall,
                                              const int* __restrict__ coarse,
                                              float* __restrict__ out) {
  __shared__ float qs[RNK];
  __shared__ float fsc[CK];
  __shared__ int gix[CK];
  __shared__ float wts[FK];
  __shared__ int fidx[FK];
  const int t = blockIdx.x, tid = threadIdx.x;
  const int lane = tid & 63, w = tid >> 6;
  if (tid < RNK) qs[tid] = q[(size_t)t * RNK + tid];
  if (tid < CK) gix[tid] = coarse[(size_t)t * CK + tid];
  __syncthreads();
  for (int c = w; c < CK; c += 4) {
    const float* kr = Kall + (size_t)gix[c] * RNK;
    float s = 0.f;
    s = fmaf(qs[lane], kr[lane], s);
    s = fmaf(qs[lane + 64], kr[lane + 64], s);
#pragma unroll
    for (int off = 32; off > 0; off >>= 1) s += __shfl_down(s, off);
    if (lane == 0) fsc[c] = s * 0.08838834764831843f;  // 1/sqrt(128)
  }
  __syncthreads();
  if (w == 0) {
    float vv = (lane < CK) ? fsc[lane] : -3e38f;
    float myv = -3e38f; int myp = 0;
    for (int kk = 0; kk < FK; kk++) {
      float v1 = vv; int p1 = lane;
#pragma unroll
      for (int off = 32; off > 0; off >>= 1) {
        float ov = __shfl_down(v1, off);
        int op = __shfl_down(p1, off);
        if (ov > v1) { v1 = ov; p1 = op; }
      }
      v1 = __shfl(v1, 0); p1 = __shfl(p1, 0);
      if (lane == kk) { myv = v1; myp = p1; }
      if (lane == p1) vv = -3e38f;
    }
    float sv = (lane < FK) ? myv : -3e38f;
    float mx = sv;
#pragma unroll
    for (int off = 8; off > 0; off >>= 1) mx = fmaxf(mx, __shfl_xor(mx, off, 16));
    float e = (lane < FK) ? expf(sv - mx) : 0.f;
    float se = e;
#pragma unroll
    for (int off = 8; off > 0; off >>= 1) se += __shfl_xor(se, off, 16);
    if (lane < FK) { wts[lane] = e / se; fidx[lane] = gix[myp]; }
  }
  __syncthreads();
  float4 a = make_float4(0.f, 0.f, 0.f, 0.f);
#pragma unroll
  for (int f = 0; f < FK; f++) {
    const float wt = wts[f];
    const float4 v = *reinterpret_cast<const float4*>(&Vall[(size_t)fidx[f] * DIM + tid * 4]);
    a.x = fmaf(wt, v.x, a.x);
    a.y = fmaf(wt, v.y, a.y);
    a.z = fmaf(wt, v.z, a.z);
    a.w = fmaf(wt, v.w, a.w);
  }
  *reinterpret_cast<float4*>(&out[(size_t)t * DIM + tid * 4]) = a;
}

// ---------------------------------------------------------------------------

extern "C" void kernel_launch(void* const* d_in, const int* in_sizes, int n_in,
                              void* d_out, int out_size, void* d_ws, size_t ws_size,
                              hipStream_t stream) {
  const float* x = (const float*)d_in[0];      // [4096][1024]
  const float* Wr = (const float*)d_in[1];     // [1024][65536]
  const float* Wenc = (const float*)d_in[2];   // [1024][128]
  const float* Kall = (const float*)d_in[3];   // [65536][128]
  const float* Vall = (const float*)d_in[4];   // [65536][1024]
  float* out = (float*)d_out;                  // [4096][1024]

  char* ws = (char*)d_ws;
  constexpr size_t OFF_WT = 0;                  // fp32 W^T    256 MB (live until rescore)
  constexpr size_t OFF_WTB = 268435456;         // bf16 W^T    128 MB (dead after gemm)
  constexpr size_t OFF_XB = 402653184;          // bf16 x        8 MB (dead after gemm)
  constexpr size_t OFF_LG = 411041792;          // bf16 logits 512 MB
  constexpr size_t OFF_CMAX = 947912704;        // chunk-max keys 4 MB
  float* WT = (float*)(ws + OFF_WT);
  unsigned short* WTb = (unsigned short*)(ws + OFF_WTB);
  unsigned short* xb = (unsigned short*)(ws + OFF_XB);
  unsigned short* Lg = (unsigned short*)(ws + OFF_LG);
  unsigned short* CmaxT = (unsigned short*)(ws + OFF_CMAX);
  // aliases into regions that are dead after k_gemm:
  int* cidx = (int*)(ws + OFF_XB);                        // 4 MB
  int* ccnt = (int*)(ws + OFF_XB + 4194304);              // 16 KB
  int* coarse = (int*)(ws + OFF_XB + 4259840);            // 320 KB
  float* q = (float*)(ws + OFF_WTB);                      // 2 MB

  k_transpose<<<65536, 256, 0, stream>>>(Wr, WT, WTb);
  k_cvt_x<<<4096, 256, 0, stream>>>(x, xb);
  k_gemm<<<8192, 512, 0, stream>>>(xb, WTb, Lg, CmaxT);
  k_pick<<<4096, 256, 0, stream>>>(CmaxT, Lg, cidx, ccnt);
  k_rescore<<<4096, 256, 0, stream>>>(x, WT, cidx, ccnt, coarse);
  k_query<<<1024, 128, 0, stream>>>(x, Wenc, q);
  k_fine<<<4096, 256, 0, stream>>>(q, Kall, Vall, coarse, out);
}

// Round 8
// 1057.313 us; speedup vs baseline: 1.1371x; 1.0012x over previous
//
#include <hip/hip_runtime.h>

#define DIM 1024
#define NKN 65536
#define TOK 4096
#define CK 20
#define FK 10
#define RNK 128
#define CAP 256
#define NCHUNK 512   // 65536 / 128 cols per GEMM block

typedef __bf16 v8bf __attribute__((ext_vector_type(8)));
typedef float v4f __attribute__((ext_vector_type(4)));

#define AS1 __attribute__((address_space(1)))
#define AS3 __attribute__((address_space(3)))

__device__ __forceinline__ unsigned short f2bf(float f) {
  // round-to-nearest-even fp32 -> bf16 (finite inputs only)
  unsigned u = __builtin_bit_cast(unsigned, f);
  u += 0x7FFFu + ((u >> 16) & 1u);
  return (unsigned short)(u >> 16);
}
__device__ __forceinline__ unsigned short bf2key(unsigned short b) {
  // monotone order-preserving key for bf16 bits
  return (b & 0x8000) ? (unsigned short)(~b) : (unsigned short)(b | 0x8000);
}

// ---------------------------------------------------------------------------
// K1: transpose W_router [DIM][NKN] -> WT fp32 [NKN][DIM] and WT bf16 [NKN][DIM]
// ---------------------------------------------------------------------------
__global__ __launch_bounds__(256) void k_transpose(const float* __restrict__ W,
                                                   float* __restrict__ WT,
                                                   unsigned short* __restrict__ WTb) {
  __shared__ float tile[32][33];
  const int n0 = (blockIdx.x & 2047) << 5;
  const int d0 = (blockIdx.x >> 11) << 5;
  const int c = threadIdx.x & 31, r0 = threadIdx.x >> 5;
#pragma unroll
  for (int i = 0; i < 4; i++) {
    int r = r0 + i * 8;
    tile[r][c] = W[(size_t)(d0 + r) * NKN + n0 + c];
  }
  __syncthreads();
#pragma unroll
  for (int i = 0; i < 4; i++) {
    int r = r0 + i * 8;
    float v = tile[c][r];  // = W[d0+c][n0+r]
    size_t o = (size_t)(n0 + r) * DIM + d0 + c;
    WT[o] = v;
    WTb[o] = f2bf(v);
  }
}

// ---------------------------------------------------------------------------
// K1b: convert x fp32 -> bf16
// ---------------------------------------------------------------------------
__global__ __launch_bounds__(256) void k_cvt_x(const float* __restrict__ x,
                                               unsigned short* __restrict__ xb) {
  const int i = blockIdx.x * 256 + threadIdx.x;
  const float4 v = reinterpret_cast<const float4*>(x)[i];
  ushort4 o;
  o.x = f2bf(v.x); o.y = f2bf(v.y); o.z = f2bf(v.z); o.w = f2bf(v.w);
  reinterpret_cast<ushort4*>(xb)[i] = o;
}

// ---------------------------------------------------------------------------
// K2: bf16 MFMA GEMM, 2-blocks/CU geometry (break the 1-block lockstep).
// 256x128 tile, BK=32, 512 threads = 8 waves (4M x 2N), per-wave C = 64x64
// -> acc 4x4 frags = 64 AGPR; VGPR 60 -> 4 waves/SIMD = 2 blocks/CU.
// LDS: 3-slot ring x 24 KB = 72 KB (2 blocks = 144 KB/CU).
// Prefetch distance 2, counted vmcnt(6)/(3)/(0), 2 barriers/tile.
// LDS layout (bank-conflict-free, corrected r8): 64-B rows, phys 16B-slot =
// lq ^ ((row>>2)&3). Banks touched by lane rm (lq fixed):
// 16*(rm&1) + 4*(lq^((rm>>2)&3)) mod 32 -- over rm=0..15 every bank hit
// exactly 2x = free (m136). Round-7's slot = lq^(rm&3) put 4 lanes on the
// same bank-quad (4-way, 6.7e7 conflicts). Rule-21: linear gload_lds dest +
// inverse-permuted global src (u = (tid&3)^((tid>>4)&3)) + same perm on read.
// Fused epilogue: per-row max over the block's 128 cols -> CmaxT[nb][row].
// ---------------------------------------------------------------------------
__global__ __launch_bounds__(512, 4) void k_gemm(const unsigned short* __restrict__ A,
                                                 const unsigned short* __restrict__ Bt,
                                                 unsigned short* __restrict__ Lg,
                                                 unsigned short* __restrict__ CmaxT) {
  __shared__ __align__(16) char lds[73728];  // ring[3]: {A 16 KB, B 8 KB}
  const int tid = threadIdx.x;
  const int lane = tid & 63, wid = tid >> 6;
  const int wm = wid >> 1, wn = wid & 1;
  const int mb = blockIdx.x & 15, nb = blockIdx.x >> 4;  // m-fast: B-panel reuse
  const int m0 = mb << 8, n0 = nb << 7;
  const int rm = lane & 15, lq = lane >> 4;
  v4f acc[4][4] = {};

  // staging (inverse-permuted src): phys row R = tid>>2, slot S = tid&3
  // logical k-slot u = S ^ ((R>>2)&3) = (tid&3) ^ ((tid>>4)&3)
  // (+128-row halves shift R by 128 == 0 mod 16 -> same key)
  const int u8 = (((tid & 3) ^ ((tid >> 4) & 3)) << 3);
  const unsigned short* aSrc = A + (size_t)(m0 + (tid >> 2)) * DIM + u8;   // rows tid>>2, +128
  const unsigned short* bSrc = Bt + (size_t)(n0 + (tid >> 2)) * DIM + u8;  // rows tid>>2 (0..127)

  // ds_read byte offsets: row*64 + (lq ^ ((row>>2)&3))*16 ; (row>>2)&3 == (rm>>2)&3
  const int sx = ((lq ^ ((rm >> 2) & 3)) << 4);
  const int aOff = (wm * 64 + rm) * 64 + sx;           // + fr*1024
  const int bOff = 16384 + (wn * 64 + rm) * 64 + sx;   // + nf*1024

#define STAGE(SLOT, KT) do { \
    char* _b = lds + (SLOT) * 24576 + tid * 16; \
    __builtin_amdgcn_global_load_lds((const AS1 void*)(aSrc + (KT)),             (AS3 void*)(_b),         16, 0, 0); \
    __builtin_amdgcn_global_load_lds((const AS1 void*)(aSrc + (KT) + 128 * DIM), (AS3 void*)(_b + 8192),  16, 0, 0); \
    __builtin_amdgcn_global_load_lds((const AS1 void*)(bSrc + (KT)),             (AS3 void*)(_b + 16384), 16, 0, 0); \
  } while (0)

#define TILE(T, VM, DOSTAGE) do { \
    if (DOSTAGE) STAGE(((T) + 2) % 3, ((T) + 2) * 32); \
    asm volatile("s_waitcnt vmcnt(" VM ")" ::: "memory"); \
    __builtin_amdgcn_s_barrier(); \
    const char* sb = lds + ((T) % 3) * 24576; \
    v8bf a0 = *(const v8bf*)(sb + aOff); \
    v8bf a1 = *(const v8bf*)(sb + aOff + 1024); \
    v8bf a2 = *(const v8bf*)(sb + aOff + 2048); \
    v8bf a3 = *(const v8bf*)(sb + aOff + 3072); \
    v8bf b0 = *(const v8bf*)(sb + bOff); \
    v8bf b1 = *(const v8bf*)(sb + bOff + 1024); \
    v8bf b2 = *(const v8bf*)(sb + bOff + 2048); \
    v8bf b3 = *(const v8bf*)(sb + bOff + 3072); \
    __builtin_amdgcn_s_setprio(1); \
    _Pragma("unroll") for (int nf = 0; nf < 4; ++nf) { \
      v8bf bb = (nf == 0) ? b0 : (nf == 1) ? b1 : (nf == 2) ? b2 : b3; \
      acc[0][nf] = __builtin_amdgcn_mfma_f32_16x16x32_bf16(a0, bb, acc[0][nf], 0, 0, 0); \
      acc[1][nf] = __builtin_amdgcn_mfma_f32_16x16x32_bf16(a1, bb, acc[1][nf], 0, 0, 0); \
      acc[2][nf] = __builtin_amdgcn_mfma_f32_16x16x32_bf16(a2, bb, acc[2][nf], 0, 0, 0); \
      acc[3][nf] = __builtin_amdgcn_mfma_f32_16x16x32_bf16(a3, bb, acc[3][nf], 0, 0, 0); \
    } \
    __builtin_amdgcn_s_setprio(0); \
    __builtin_amdgcn_s_barrier(); \
  } while (0)

  // prologue: stage tiles 0,1 (6 loads in flight)
  STAGE(0, 0);
  STAGE(1, 32);

  for (int t = 0; t < 30; ++t) {
    TILE(t, "6", true);
  }
  TILE(30, "3", false);
  TILE(31, "0", false);
#undef TILE
#undef STAGE

  // ---- epilogue ----
  // C/D layout (verified m89/m91): n = rm, m = lq*4 + reg
  const int mr = lq * 4;
  float rmax[4][4];
#pragma unroll
  for (int fr = 0; fr < 4; ++fr) {
#pragma unroll
    for (int r = 0; r < 4; ++r) {
      float mx = acc[fr][0][r];
#pragma unroll
      for (int nf = 1; nf < 4; ++nf) mx = fmaxf(mx, acc[fr][nf][r]);
      rmax[fr][r] = mx;
    }
#pragma unroll
    for (int nf = 0; nf < 4; ++nf) {
      const int mrow = m0 + wm * 64 + fr * 16 + mr;
      const int ncol = n0 + wn * 64 + nf * 16 + rm;
#pragma unroll
      for (int r = 0; r < 4; ++r)
        Lg[(size_t)(mrow + r) * NKN + ncol] = f2bf(acc[fr][nf][r]);
    }
  }
  // reduce row-max across the 16 rm lanes (xor<16 stays within the group)
#pragma unroll
  for (int fr = 0; fr < 4; ++fr)
#pragma unroll
    for (int r = 0; r < 4; ++r) {
#pragma unroll
      for (int off = 1; off < 16; off <<= 1)
        rmax[fr][r] = fmaxf(rmax[fr][r], __shfl_xor(rmax[fr][r], off));
    }
  // cross-wave (wn) combine via LDS (slot-0 region, all reads retired)
  __syncthreads();
  float* smax = (float*)lds;  // [2][256]
  if (rm == 0) {
#pragma unroll
    for (int fr = 0; fr < 4; ++fr)
#pragma unroll
      for (int r = 0; r < 4; ++r)
        smax[wn * 256 + wm * 64 + fr * 16 + mr + r] = rmax[fr][r];
  }
  __syncthreads();
  if (tid < 256) {
    float v = fmaxf(smax[tid], smax[256 + tid]);
    CmaxT[(size_t)nb * TOK + m0 + tid] = bf2key(f2bf(v));
  }
}

// ---------------------------------------------------------------------------
// K3: per-token candidate pick from chunk maxes (CmaxT layout [NCHUNK][TOK]).
// tau = 32nd-largest chunk-max key (EXACT); collect all entries with key >=
// tau. Superset of bf16-top-32 (the 32 chunk-maxes are 32 distinct elements
// >= tau). Reads only qualifying 128-col chunks.
// ---------------------------------------------------------------------------
__global__ __launch_bounds__(256) void k_pick(const unsigned short* __restrict__ CmaxT,
                                              const unsigned short* __restrict__ Lg,
                                              int* __restrict__ cidx,
                                              int* __restrict__ ccnt) {
  __shared__ unsigned short keys[NCHUNK];
  __shared__ int qlist[NCHUNK];
  __shared__ int qn, scnt, bsS;
  const int t = blockIdx.x, tid = threadIdx.x;
  const int lane = tid & 63, w = tid >> 6;
  keys[tid] = CmaxT[(size_t)tid * TOK + t];
  keys[tid + 256] = CmaxT[(size_t)(tid + 256) * TOK + t];
  if (tid == 0) { qn = 0; scnt = 0; }
  __syncthreads();
  if (w == 0) {
    int v[8];
#pragma unroll
    for (int j = 0; j < 8; j++) v[j] = keys[lane * 8 + j];
    int t32 = 0;
    for (int it = 0; it < 32; it++) {
      int lm = v[0];
#pragma unroll
      for (int j = 1; j < 8; j++) lm = max(lm, v[j]);
      int gm = lm;
#pragma unroll
      for (int off = 32; off > 0; off >>= 1) gm = max(gm, __shfl_xor(gm, off));
      unsigned long long msk = __ballot(lm == gm);
      if (lane == __ffsll((long long)msk) - 1) {
        bool done = false;
#pragma unroll
        for (int j = 0; j < 8; j++)
          if (!done && v[j] == gm) { v[j] = -1; done = true; }
      }
      t32 = gm;
    }
    if (lane == 0) bsS = t32;
  }
  __syncthreads();
  const int bs = bsS;
  for (int c = tid; c < NCHUNK; c += 256)
    if ((int)keys[c] >= bs) { int p = atomicAdd(&qn, 1); qlist[p] = c; }
  __syncthreads();
  const int nq = qn;
  const int sub = tid >> 7, e = tid & 127;
  for (int qi = sub; qi < nq; qi += 2) {
    const int col = qlist[qi] * 128 + e;
    unsigned short key = bf2key(Lg[(size_t)t * NKN + col]);
    if ((int)key >= bs) {
      int p = atomicAdd(&scnt, 1);
      if (p < CAP) cidx[(size_t)t * CAP + p] = col;
    }
  }
  __syncthreads();
  if (tid == 0) ccnt[t] = min(scnt, CAP);
}

// ---------------------------------------------------------------------------
// K4: exact fp64 rescore of candidates + exact top-20 selection
// ---------------------------------------------------------------------------
__global__ __launch_bounds__(256) void k_rescore(const float* __restrict__ x,
                                                 const float* __restrict__ WT,
                                                 const int* __restrict__ cidx,
                                                 const int* __restrict__ ccnt,
                                                 int* __restrict__ coarse) {
  __shared__ float xs[DIM];
  __shared__ double sc[CAP];
  __shared__ int ci[CAP];
  const int t = blockIdx.x, tid = threadIdx.x;
  const int lane = tid & 63, w = tid >> 6;
  const int cnt = ccnt[t];
  for (int i = tid; i < DIM; i += 256) xs[i] = x[(size_t)t * DIM + i];
  for (int i = tid; i < CAP; i += 256) {
    sc[i] = -1e300;
    ci[i] = (i < cnt) ? cidx[(size_t)t * CAP + i] : 0;
  }
  __syncthreads();
  for (int c = w; c < cnt; c += 4) {
    const float* wr = WT + (size_t)ci[c] * DIM;
    double sacc = 0.0;
#pragma unroll 4
    for (int i = lane; i < DIM; i += 64) sacc += (double)xs[i] * (double)wr[i];
#pragma unroll
    for (int off = 32; off > 0; off >>= 1) sacc += __shfl_down(sacc, off);
    if (lane == 0) sc[c] = sacc;
  }
  __syncthreads();
  if (w == 0) {
    double v[4];
    int ix[4];
#pragma unroll
    for (int j = 0; j < 4; j++) { v[j] = sc[lane + j * 64]; ix[j] = lane + j * 64; }
    for (int kk = 0; kk < CK; kk++) {
      double v1 = v[0]; int i1 = ix[0];
#pragma unroll
      for (int j = 1; j < 4; j++)
        if (v[j] > v1) { v1 = v[j]; i1 = ix[j]; }
#pragma unroll
      for (int off = 32; off > 0; off >>= 1) {
        double ov = __shfl_down(v1, off);
        int oi = __shfl_down(i1, off);
        if (ov > v1) { v1 = ov; i1 = oi; }
      }
      i1 = __shfl(i1, 0);
      if (lane == 0) coarse[(size_t)t * CK + kk] = ci[i1];
#pragma unroll
      for (int j = 0; j < 4; j++)
        if (i1 == ix[j]) v[j] = -1e300;
    }
  }
}

// ---------------------------------------------------------------------------
// K5: query = x @ W_enc
// ---------------------------------------------------------------------------
__global__ __launch_bounds__(128) void k_query(const float* __restrict__ x,
                                               const float* __restrict__ Wenc,
                                               float* __restrict__ q) {
  const int j = threadIdx.x;
  const int t0 = blockIdx.x * 4;
  float s0 = 0.f, s1 = 0.f, s2 = 0.f, s3 = 0.f;
  const float* x0 = x + (size_t)t0 * DIM;
  for (int d = 0; d < DIM; d++) {
    float wv = Wenc[d * RNK + j];
    s0 = fmaf(x0[d], wv, s0);
    s1 = fmaf(x0[DIM + d], wv, s1);
    s2 = fmaf(x0[2 * DIM + d], wv, s2);
    s3 = fmaf(x0[3 * DIM + d], wv, s3);
  }
  q[(size_t)t0 * RNK + j] = s0;
  q[(size_t)(t0 + 1) * RNK + j] = s1;
  q[(size_t)(t0 + 2) * RNK + j] = s2;
  q[(size_t)(t0 + 3) * RNK + j] = s3;
}

// ---------------------------------------------------------------------------
// K6: fine scores vs 20 candidates, top-10, softmax, weighted V blend
// ---------------------------------------------------------------------------
__global__ __launch_bounds__(256) void k_fine(const float* __restrict__ q,
                                              const float* __restrict__ Kall,
                                              const float* __restrict__ Vall,
                                              const int* __restrict__ coarse,
                                              float* __restrict__ out) {
  __shared__ float qs[RNK];
  __shared__ float fsc[CK];
  __shared__ int gix[CK];
  __shared__ float wts[FK];
  __shared__ int fidx[FK];
  const int t = blockIdx.x, tid = threadIdx.x;
  const int lane = tid & 63, w = tid >> 6;
  if (tid < RNK) qs[tid] = q[(size_t)t * RNK + tid];
  if (tid < CK) gix[tid] = coarse[(size_t)t * CK + tid];
  __syncthreads();
  for (int c = w; c < CK; c += 4) {
    const float* kr = Kall + (size_t)gix[c] * RNK;
    float s = 0.f;
    s = fmaf(qs[lane], kr[lane], s);
    s = fmaf(qs[lane + 64], kr[lane + 64], s);
#pragma unroll
    for (int off = 32; off > 0; off >>= 1) s += __shfl_down(s, off);
    if (lane == 0) fsc[c] = s * 0.08838834764831843f;  // 1/sqrt(128)
  }
  __syncthreads();
  if (w == 0) {
    float vv = (lane < CK) ? fsc[lane] : -3e38f;
    float myv = -3e38f; int myp = 0;
    for (int kk = 0; kk < FK; kk++) {
      float v1 = vv; int p1 = lane;
#pragma unroll
      for (int off = 32; off > 0; off >>= 1) {
        float ov = __shfl_down(v1, off);
        int op = __shfl_down(p1, off);
        if (ov > v1) { v1 = ov; p1 = op; }
      }
      v1 = __shfl(v1, 0); p1 = __shfl(p1, 0);
      if (lane == kk) { myv = v1; myp = p1; }
      if (lane == p1) vv = -3e38f;
    }
    float sv = (lane < FK) ? myv : -3e38f;
    float mx = sv;
#pragma unroll
    for (int off = 8; off > 0; off >>= 1) mx = fmaxf(mx, __shfl_xor(mx, off, 16));
    float e = (lane < FK) ? expf(sv - mx) : 0.f;
    float se = e;
#pragma unroll
    for (int off = 8; off > 0; off >>= 1) se += __shfl_xor(se, off, 16);
    if (lane < FK) { wts[lane] = e / se; fidx[lane] = gix[myp]; }
  }
  __syncthreads();
  float4 a = make_float4(0.f, 0.f, 0.f, 0.f);
#pragma unroll
  for (int f = 0; f < FK; f++) {
    const float wt = wts[f];
    const float4 v = *reinterpret_cast<const float4*>(&Vall[(size_t)fidx[f] * DIM + tid * 4]);
    a.x = fmaf(wt, v.x, a.x);
    a.y = fmaf(wt, v.y, a.y);
    a.z = fmaf(wt, v.z, a.z);
    a.w = fmaf(wt, v.w, a.w);
  }
  *reinterpret_cast<float4*>(&out[(size_t)t * DIM + tid * 4]) = a;
}

// ---------------------------------------------------------------------------

extern "C" void kernel_launch(void* const* d_in, const int* in_sizes, int n_in,
                              void* d_out, int out_size, void* d_ws, size_t ws_size,
                              hipStream_t stream) {
  const float* x = (const float*)d_in[0];      // [4096][1024]
  const float* Wr = (const float*)d_in[1];     // [1024][65536]
  const float* Wenc = (const float*)d_in[2];   // [1024][128]
  const float* Kall = (const float*)d_in[3];   // [65536][128]
  const float* Vall = (const float*)d_in[4];   // [65536][1024]
  float* out = (float*)d_out;                  // [4096][1024]

  char* ws = (char*)d_ws;
  constexpr size_t OFF_WT = 0;                  // fp32 W^T    256 MB (live until rescore)
  constexpr size_t OFF_WTB = 268435456;         // bf16 W^T    128 MB (dead after gemm)
  constexpr size_t OFF_XB = 402653184;          // bf16 x        8 MB (dead after gemm)
  constexpr size_t OFF_LG = 411041792;          // bf16 logits 512 MB
  constexpr size_t OFF_CMAX = 947912704;        // chunk-max keys 4 MB
  float* WT = (float*)(ws + OFF_WT);
  unsigned short* WTb = (unsigned short*)(ws + OFF_WTB);
  unsigned short* xb = (unsigned short*)(ws + OFF_XB);
  unsigned short* Lg = (unsigned short*)(ws + OFF_LG);
  unsigned short* CmaxT = (unsigned short*)(ws + OFF_CMAX);
  // aliases into regions that are dead after k_gemm:
  int* cidx = (int*)(ws + OFF_XB);                        // 4 MB
  int* ccnt = (int*)(ws + OFF_XB + 4194304);              // 16 KB
  int* coarse = (int*)(ws + OFF_XB + 4259840);            // 320 KB
  float* q = (float*)(ws + OFF_WTB);                      // 2 MB

  k_transpose<<<65536, 256, 0, stream>>>(Wr, WT, WTb);
  k_cvt_x<<<4096, 256, 0, stream>>>(x, xb);
  k_gemm<<<8192, 512, 0, stream>>>(xb, WTb, Lg, CmaxT);
  k_pick<<<4096, 256, 0, stream>>>(CmaxT, Lg, cidx, ccnt);
  k_rescore<<<4096, 256, 0, stream>>>(x, WT, cidx, ccnt, coarse);
  k_query<<<1024, 128, 0, stream>>>(x, Wenc, q);
  k_fine<<<4096, 256, 0, stream>>>(q, Kall, Vall, coarse, out);
}

// Round 9
// 1045.364 us; speedup vs baseline: 1.1501x; 1.0114x over previous
//
#include <hip/hip_runtime.h>

#define DIM 1024
#define NKN 65536
#define TOK 4096
#define CK 20
#define FK 10
#define RNK 128
#define CAP 256
#define NCHUNK 512   // 65536 / 128 cols per GEMM block

typedef __bf16 v8bf __attribute__((ext_vector_type(8)));
typedef float v4f __attribute__((ext_vector_type(4)));

#define AS1 __attribute__((address_space(1)))
#define AS3 __attribute__((address_space(3)))

__device__ __forceinline__ unsigned short f2bf(float f) {
  // round-to-nearest-even fp32 -> bf16 (finite inputs only)
  unsigned u = __builtin_bit_cast(unsigned, f);
  u += 0x7FFFu + ((u >> 16) & 1u);
  return (unsigned short)(u >> 16);
}
__device__ __forceinline__ unsigned short bf2key(unsigned short b) {
  // monotone order-preserving key for bf16 bits
  return (b & 0x8000) ? (unsigned short)(~b) : (unsigned short)(b | 0x8000);
}

// ---------------------------------------------------------------------------
// K1: transpose W_router [DIM][NKN] -> WT fp32 [NKN][DIM] and WT bf16 [NKN][DIM]
// ---------------------------------------------------------------------------
__global__ __launch_bounds__(256) void k_transpose(const float* __restrict__ W,
                                                   float* __restrict__ WT,
                                                   unsigned short* __restrict__ WTb) {
  __shared__ float tile[32][33];
  const int n0 = (blockIdx.x & 2047) << 5;
  const int d0 = (blockIdx.x >> 11) << 5;
  const int c = threadIdx.x & 31, r0 = threadIdx.x >> 5;
#pragma unroll
  for (int i = 0; i < 4; i++) {
    int r = r0 + i * 8;
    tile[r][c] = W[(size_t)(d0 + r) * NKN + n0 + c];
  }
  __syncthreads();
#pragma unroll
  for (int i = 0; i < 4; i++) {
    int r = r0 + i * 8;
    float v = tile[c][r];  // = W[d0+c][n0+r]
    size_t o = (size_t)(n0 + r) * DIM + d0 + c;
    WT[o] = v;
    WTb[o] = f2bf(v);
  }
}

// ---------------------------------------------------------------------------
// K1b: convert x fp32 -> bf16
// ---------------------------------------------------------------------------
__global__ __launch_bounds__(256) void k_cvt_x(const float* __restrict__ x,
                                               unsigned short* __restrict__ xb) {
  const int i = blockIdx.x * 256 + threadIdx.x;
  const float4 v = reinterpret_cast<const float4*>(x)[i];
  ushort4 o;
  o.x = f2bf(v.x); o.y = f2bf(v.y); o.z = f2bf(v.z); o.w = f2bf(v.w);
  reinterpret_cast<ushort4*>(xb)[i] = o;
}

// ---------------------------------------------------------------------------
// K2: bf16 MFMA GEMM, 2-blocks/CU geometry + conflict-free LDS (r9).
// 256x128 tile, BK=32, 512 threads = 8 waves (4M x 2N), per-wave C = 64x64
// -> acc 64 AGPR, VGPR ~60 -> 4 waves/SIMD = 2 blocks/CU.
// LDS: 3-slot ring x 24 KB = 72 KB (2 blocks = 144 KB/CU).
// Prefetch distance 2, counted vmcnt(6)/(3)/(0), 2 barriers/tile.
// LDS swizzle (r9 FIX): 64-B rows, phys 16B-slot = lq ^ ((row>>1)&3).
// b128 conflict model: LDS serves 8 consecutive lanes/cycle; quad
// q = 4*(rm&1) + slot must be a permutation of 0..7 within each 8-lane
// group. key=(rm>>1)&3 makes (rm&1,key) bijective over 8 consecutive rm
// -> permutation (r4-6 measured 0 conflicts). r7 key=rm&3 and r8 key=
// (rm>>2)&3 both gave 2-way (counter clipped at 2^26). Rule-21: linear
// gload_lds dest + inverse-permuted global src (u=(tid&3)^((tid>>3)&3),
// phys row R=tid>>2, key=(R>>1)&3=(tid>>3)&3) + same perm on ds_read.
// Fused epilogue: per-row max over the block's 128 cols -> CmaxT[nb][row].
// ---------------------------------------------------------------------------
__global__ __launch_bounds__(512, 4) void k_gemm(const unsigned short* __restrict__ A,
                                                 const unsigned short* __restrict__ Bt,
                                                 unsigned short* __restrict__ Lg,
                                                 unsigned short* __restrict__ CmaxT) {
  __shared__ __align__(16) char lds[73728];  // ring[3]: {A 16 KB, B 8 KB}
  const int tid = threadIdx.x;
  const int lane = tid & 63, wid = tid >> 6;
  const int wm = wid >> 1, wn = wid & 1;
  const int mb = blockIdx.x & 15, nb = blockIdx.x >> 4;  // m-fast: B-panel reuse
  const int m0 = mb << 8, n0 = nb << 7;
  const int rm = lane & 15, lq = lane >> 4;
  v4f acc[4][4] = {};

  // staging (inverse-permuted src): phys row R = tid>>2, slot S = tid&3
  // logical k-slot u = S ^ ((R>>1)&3) = (tid&3) ^ ((tid>>3)&3)
  // (+128-row half shifts R by 128 == 0 mod 8 -> same key)
  const int u8 = (((tid & 3) ^ ((tid >> 3) & 3)) << 3);
  const unsigned short* aSrc = A + (size_t)(m0 + (tid >> 2)) * DIM + u8;   // rows tid>>2, +128
  const unsigned short* bSrc = Bt + (size_t)(n0 + (tid >> 2)) * DIM + u8;  // rows tid>>2 (0..127)

  // ds_read byte offsets: row*64 + (lq ^ ((row>>1)&3))*16 ; (row>>1)&3 == (rm>>1)&3
  const int sx = ((lq ^ ((rm >> 1) & 3)) << 4);
  const int aOff = (wm * 64 + rm) * 64 + sx;           // + fr*1024
  const int bOff = 16384 + (wn * 64 + rm) * 64 + sx;   // + nf*1024

#define STAGE(SLOT, KT) do { \
    char* _b = lds + (SLOT) * 24576 + tid * 16; \
    __builtin_amdgcn_global_load_lds((const AS1 void*)(aSrc + (KT)),             (AS3 void*)(_b),         16, 0, 0); \
    __builtin_amdgcn_global_load_lds((const AS1 void*)(aSrc + (KT) + 128 * DIM), (AS3 void*)(_b + 8192),  16, 0, 0); \
    __builtin_amdgcn_global_load_lds((const AS1 void*)(bSrc + (KT)),             (AS3 void*)(_b + 16384), 16, 0, 0); \
  } while (0)

#define TILE(T, VM, DOSTAGE) do { \
    if (DOSTAGE) STAGE(((T) + 2) % 3, ((T) + 2) * 32); \
    asm volatile("s_waitcnt vmcnt(" VM ")" ::: "memory"); \
    __builtin_amdgcn_s_barrier(); \
    const char* sb = lds + ((T) % 3) * 24576; \
    v8bf a0 = *(const v8bf*)(sb + aOff); \
    v8bf a1 = *(const v8bf*)(sb + aOff + 1024); \
    v8bf a2 = *(const v8bf*)(sb + aOff + 2048); \
    v8bf a3 = *(const v8bf*)(sb + aOff + 3072); \
    v8bf b0 = *(const v8bf*)(sb + bOff); \
    v8bf b1 = *(const v8bf*)(sb + bOff + 1024); \
    v8bf b2 = *(const v8bf*)(sb + bOff + 2048); \
    v8bf b3 = *(const v8bf*)(sb + bOff + 3072); \
    __builtin_amdgcn_s_setprio(1); \
    _Pragma("unroll") for (int nf = 0; nf < 4; ++nf) { \
      v8bf bb = (nf == 0) ? b0 : (nf == 1) ? b1 : (nf == 2) ? b2 : b3; \
      acc[0][nf] = __builtin_amdgcn_mfma_f32_16x16x32_bf16(a0, bb, acc[0][nf], 0, 0, 0); \
      acc[1][nf] = __builtin_amdgcn_mfma_f32_16x16x32_bf16(a1, bb, acc[1][nf], 0, 0, 0); \
      acc[2][nf] = __builtin_amdgcn_mfma_f32_16x16x32_bf16(a2, bb, acc[2][nf], 0, 0, 0); \
      acc[3][nf] = __builtin_amdgcn_mfma_f32_16x16x32_bf16(a3, bb, acc[3][nf], 0, 0, 0); \
    } \
    __builtin_amdgcn_s_setprio(0); \
    __builtin_amdgcn_s_barrier(); \
  } while (0)

  // prologue: stage tiles 0,1 (6 loads in flight)
  STAGE(0, 0);
  STAGE(1, 32);

  for (int t = 0; t < 30; ++t) {
    TILE(t, "6", true);
  }
  TILE(30, "3", false);
  TILE(31, "0", false);
#undef TILE
#undef STAGE

  // ---- epilogue ----
  // C/D layout (verified m89/m91): n = rm, m = lq*4 + reg
  const int mr = lq * 4;
  float rmax[4][4];
#pragma unroll
  for (int fr = 0; fr < 4; ++fr) {
#pragma unroll
    for (int r = 0; r < 4; ++r) {
      float mx = acc[fr][0][r];
#pragma unroll
      for (int nf = 1; nf < 4; ++nf) mx = fmaxf(mx, acc[fr][nf][r]);
      rmax[fr][r] = mx;
    }
#pragma unroll
    for (int nf = 0; nf < 4; ++nf) {
      const int mrow = m0 + wm * 64 + fr * 16 + mr;
      const int ncol = n0 + wn * 64 + nf * 16 + rm;
#pragma unroll
      for (int r = 0; r < 4; ++r)
        Lg[(size_t)(mrow + r) * NKN + ncol] = f2bf(acc[fr][nf][r]);
    }
  }
  // reduce row-max across the 16 rm lanes (xor<16 stays within the group)
#pragma unroll
  for (int fr = 0; fr < 4; ++fr)
#pragma unroll
    for (int r = 0; r < 4; ++r) {
#pragma unroll
      for (int off = 1; off < 16; off <<= 1)
        rmax[fr][r] = fmaxf(rmax[fr][r], __shfl_xor(rmax[fr][r], off));
    }
  // cross-wave (wn) combine via LDS (slot-0 region, all reads retired)
  __syncthreads();
  float* smax = (float*)lds;  // [2][256]
  if (rm == 0) {
#pragma unroll
    for (int fr = 0; fr < 4; ++fr)
#pragma unroll
      for (int r = 0; r < 4; ++r)
        smax[wn * 256 + wm * 64 + fr * 16 + mr + r] = rmax[fr][r];
  }
  __syncthreads();
  if (tid < 256) {
    float v = fmaxf(smax[tid], smax[256 + tid]);
    CmaxT[(size_t)nb * TOK + m0 + tid] = bf2key(f2bf(v));
  }
}

// ---------------------------------------------------------------------------
// K3: per-token candidate pick from chunk maxes (CmaxT layout [NCHUNK][TOK]).
// tau = 32nd-largest chunk-max key (EXACT); collect all entries with key >=
// tau. Superset of bf16-top-32 (the 32 chunk-maxes are 32 distinct elements
// >= tau). Reads only qualifying 128-col chunks.
// ---------------------------------------------------------------------------
__global__ __launch_bounds__(256) void k_pick(const unsigned short* __restrict__ CmaxT,
                                              const unsigned short* __restrict__ Lg,
                                              int* __restrict__ cidx,
                                              int* __restrict__ ccnt) {
  __shared__ unsigned short keys[NCHUNK];
  __shared__ int qlist[NCHUNK];
  __shared__ int qn, scnt, bsS;
  const int t = blockIdx.x, tid = threadIdx.x;
  const int lane = tid & 63, w = tid >> 6;
  keys[tid] = CmaxT[(size_t)tid * TOK + t];
  keys[tid + 256] = CmaxT[(size_t)(tid + 256) * TOK + t];
  if (tid == 0) { qn = 0; scnt = 0; }
  __syncthreads();
  if (w == 0) {
    int v[8];
#pragma unroll
    for (int j = 0; j < 8; j++) v[j] = keys[lane * 8 + j];
    int t32 = 0;
    for (int it = 0; it < 32; it++) {
      int lm = v[0];
#pragma unroll
      for (int j = 1; j < 8; j++) lm = max(lm, v[j]);
      int gm = lm;
#pragma unroll
      for (int off = 32; off > 0; off >>= 1) gm = max(gm, __shfl_xor(gm, off));
      unsigned long long msk = __ballot(lm == gm);
      if (lane == __ffsll((long long)msk) - 1) {
        bool done = false;
#pragma unroll
        for (int j = 0; j < 8; j++)
          if (!done && v[j] == gm) { v[j] = -1; done = true; }
      }
      t32 = gm;
    }
    if (lane == 0) bsS = t32;
  }
  __syncthreads();
  const int bs = bsS;
  for (int c = tid; c < NCHUNK; c += 256)
    if ((int)keys[c] >= bs) { int p = atomicAdd(&qn, 1); qlist[p] = c; }
  __syncthreads();
  const int nq = qn;
  const int sub = tid >> 7, e = tid & 127;
  for (int qi = sub; qi < nq; qi += 2) {
    const int col = qlist[qi] * 128 + e;
    unsigned short key = bf2key(Lg[(size_t)t * NKN + col]);
    if ((int)key >= bs) {
      int p = atomicAdd(&scnt, 1);
      if (p < CAP) cidx[(size_t)t * CAP + p] = col;
    }
  }
  __syncthreads();
  if (tid == 0) ccnt[t] = min(scnt, CAP);
}

// ---------------------------------------------------------------------------
// K4: exact fp64 rescore of candidates + exact top-20 selection
// ---------------------------------------------------------------------------
__global__ __launch_bounds__(256) void k_rescore(const float* __restrict__ x,
                                                 const float* __restrict__ WT,
                                                 const int* __restrict__ cidx,
                                                 const int* __restrict__ ccnt,
                                                 int* __restrict__ coarse) {
  __shared__ float xs[DIM];
  __shared__ double sc[CAP];
  __shared__ int ci[CAP];
  const int t = blockIdx.x, tid = threadIdx.x;
  const int lane = tid & 63, w = tid >> 6;
  const int cnt = ccnt[t];
  for (int i = tid; i < DIM; i += 256) xs[i] = x[(size_t)t * DIM + i];
  for (int i = tid; i < CAP; i += 256) {
    sc[i] = -1e300;
    ci[i] = (i < cnt) ? cidx[(size_t)t * CAP + i] : 0;
  }
  __syncthreads();
  for (int c = w; c < cnt; c += 4) {
    const float* wr = WT + (size_t)ci[c] * DIM;
    double sacc = 0.0;
#pragma unroll 4
    for (int i = lane; i < DIM; i += 64) sacc += (double)xs[i] * (double)wr[i];
#pragma unroll
    for (int off = 32; off > 0; off >>= 1) sacc += __shfl_down(sacc, off);
    if (lane == 0) sc[c] = sacc;
  }
  __syncthreads();
  if (w == 0) {
    double v[4];
    int ix[4];
#pragma unroll
    for (int j = 0; j < 4; j++) { v[j] = sc[lane + j * 64]; ix[j] = lane + j * 64; }
    for (int kk = 0; kk < CK; kk++) {
      double v1 = v[0]; int i1 = ix[0];
#pragma unroll
      for (int j = 1; j < 4; j++)
        if (v[j] > v1) { v1 = v[j]; i1 = ix[j]; }
#pragma unroll
      for (int off = 32; off > 0; off >>= 1) {
        double ov = __shfl_down(v1, off);
        int oi = __shfl_down(i1, off);
        if (ov > v1) { v1 = ov; i1 = oi; }
      }
      i1 = __shfl(i1, 0);
      if (lane == 0) coarse[(size_t)t * CK + kk] = ci[i1];
#pragma unroll
      for (int j = 0; j < 4; j++)
        if (i1 == ix[j]) v[j] = -1e300;
    }
  }
}

// ---------------------------------------------------------------------------
// K5: query = x @ W_enc
// ---------------------------------------------------------------------------
__global__ __launch_bounds__(128) void k_query(const float* __restrict__ x,
                                               const float* __restrict__ Wenc,
                                               float* __restrict__ q) {
  const int j = threadIdx.x;
  const int t0 = blockIdx.x * 4;
  float s0 = 0.f, s1 = 0.f, s2 = 0.f, s3 = 0.f;
  const float* x0 = x + (size_t)t0 * DIM;
  for (int d = 0; d < DIM; d++) {
    float wv = Wenc[d * RNK + j];
    s0 = fmaf(x0[d], wv, s0);
    s1 = fmaf(x0[DIM + d], wv, s1);
    s2 = fmaf(x0[2 * DIM + d], wv, s2);
    s3 = fmaf(x0[3 * DIM + d], wv, s3);
  }
  q[(size_t)t0 * RNK + j] = s0;
  q[(size_t)(t0 + 1) * RNK + j] = s1;
  q[(size_t)(t0 + 2) * RNK + j] = s2;
  q[(size_t)(t0 + 3) * RNK + j] = s3;
}

// ---------------------------------------------------------------------------
// K6: fine scores vs 20 candidates, top-10, softmax, weighted V blend
// ---------------------------------------------------------------------------
__global__ __launch_bounds__(256) void k_fine(const float* __restrict__ q,
                                              const float* __restrict__ Kall,
                                              const float* __restrict__ Vall,
                                              const int* __restrict__ coarse,
                                              float* __restrict__ out) {
  __shared__ float qs[RNK];
  __shared__ float fsc[CK];
  __shared__ int gix[CK];
  __shared__ float wts[FK];
  __shared__ int fidx[FK];
  const int t = blockIdx.x, tid = threadIdx.x;
  const int lane = tid & 63, w = tid >> 6;
  if (tid < RNK) qs[tid] = q[(size_t)t * RNK + tid];
  if (tid < CK) gix[tid] = coarse[(size_t)t * CK + tid];
  __syncthreads();
  for (int c = w; c < CK; c += 4) {
    const float* kr = Kall + (size_t)gix[c] * RNK;
    float s = 0.f;
    s = fmaf(qs[lane], kr[lane], s);
    s = fmaf(qs[lane + 64], kr[lane + 64], s);
#pragma unroll
    for (int off = 32; off > 0; off >>= 1) s += __shfl_down(s, off);
    if (lane == 0) fsc[c] = s * 0.08838834764831843f;  // 1/sqrt(128)
  }
  __syncthreads();
  if (w == 0) {
    float vv = (lane < CK) ? fsc[lane] : -3e38f;
    float myv = -3e38f; int myp = 0;
    for (int kk = 0; kk < FK; kk++) {
      float v1 = vv; int p1 = lane;
#pragma unroll
      for (int off = 32; off > 0; off >>= 1) {
        float ov = __shfl_down(v1, off);
        int op = __shfl_down(p1, off);
        if (ov > v1) { v1 = ov; p1 = op; }
      }
      v1 = __shfl(v1, 0); p1 = __shfl(p1, 0);
      if (lane == kk) { myv = v1; myp = p1; }
      if (lane == p1) vv = -3e38f;
    }
    float sv = (lane < FK) ? myv : -3e38f;
    float mx = sv;
#pragma unroll
    for (int off = 8; off > 0; off >>= 1) mx = fmaxf(mx, __shfl_xor(mx, off, 16));
    float e = (lane < FK) ? expf(sv - mx) : 0.f;
    float se = e;
#pragma unroll
    for (int off = 8; off > 0; off >>= 1) se += __shfl_xor(se, off, 16);
    if (lane < FK) { wts[lane] = e / se; fidx[lane] = gix[myp]; }
  }
  __syncthreads();
  float4 a = make_float4(0.f, 0.f, 0.f, 0.f);
#pragma unroll
  for (int f = 0; f < FK; f++) {
    const float wt = wts[f];
    const float4 v = *reinterpret_cast<const float4*>(&Vall[(size_t)fidx[f] * DIM + tid * 4]);
    a.x = fmaf(wt, v.x, a.x);
    a.y = fmaf(wt, v.y, a.y);
    a.z = fmaf(wt, v.z, a.z);
    a.w = fmaf(wt, v.w, a.w);
  }
  *reinterpret_cast<float4*>(&out[(size_t)t * DIM + tid * 4]) = a;
}

// ---------------------------------------------------------------------------

extern "C" void kernel_launch(void* const* d_in, const int* in_sizes, int n_in,
                              void* d_out, int out_size, void* d_ws, size_t ws_size,
                              hipStream_t stream) {
  const float* x = (const float*)d_in[0];      // [4096][1024]
  const float* Wr = (const float*)d_in[1];     // [1024][65536]
  const float* Wenc = (const float*)d_in[2];   // [1024][128]
  const float* Kall = (const float*)d_in[3];   // [65536][128]
  const float* Vall = (const float*)d_in[4];   // [65536][1024]
  float* out = (float*)d_out;                  // [4096][1024]

  char* ws = (char*)d_ws;
  constexpr size_t OFF_WT = 0;                  // fp32 W^T    256 MB (live until rescore)
  constexpr size_t OFF_WTB = 268435456;         // bf16 W^T    128 MB (dead after gemm)
  constexpr size_t OFF_XB = 402653184;          // bf16 x        8 MB (dead after gemm)
  constexpr size_t OFF_LG = 411041792;          // bf16 logits 512 MB
  constexpr size_t OFF_CMAX = 947912704;        // chunk-max keys 4 MB
  float* WT = (float*)(ws + OFF_WT);
  unsigned short* WTb = (unsigned short*)(ws + OFF_WTB);
  unsigned short* xb = (unsigned short*)(ws + OFF_XB);
  unsigned short* Lg = (unsigned short*)(ws + OFF_LG);
  unsigned short* CmaxT = (unsigned short*)(ws + OFF_CMAX);
  // aliases into regions that are dead after k_gemm:
  int* cidx = (int*)(ws + OFF_XB);                        // 4 MB
  int* ccnt = (int*)(ws + OFF_XB + 4194304);              // 16 KB
  int* coarse = (int*)(ws + OFF_XB + 4259840);            // 320 KB
  float* q = (float*)(ws + OFF_WTB);                      // 2 MB

  k_transpose<<<65536, 256, 0, stream>>>(Wr, WT, WTb);
  k_cvt_x<<<4096, 256, 0, stream>>>(x, xb);
  k_gemm<<<8192, 512, 0, stream>>>(xb, WTb, Lg, CmaxT);
  k_pick<<<4096, 256, 0, stream>>>(CmaxT, Lg, cidx, ccnt);
  k_rescore<<<4096, 256, 0, stream>>>(x, WT, cidx, ccnt, coarse);
  k_query<<<1024, 128, 0, stream>>>(x, Wenc, q);
  k_fine<<<4096, 256, 0, stream>>>(q, Kall, Vall, coarse, out);
}